// Round 2
// baseline (367.834 us; speedup 1.0000x reference)
//
#include <hip/hip_runtime.h>
#include <hip/hip_bf16.h>

#define N_NODES  50000
#define N_EDGES  640000
#define IN_FEATS 512
#define HID      128
#define OUT_FEATS 128
#define N_GRAPHS 256

#define SCAN_CHUNK 1024
#define SCAN_BLOCKS ((N_NODES + SCAN_CHUNK - 1) / SCAN_CHUNK)   // 49

typedef __attribute__((ext_vector_type(8))) short short8;
typedef __attribute__((ext_vector_type(4))) float f32x4;

__device__ __forceinline__ float bf2f(unsigned u16) {
    return __uint_as_float(u16 << 16);
}
__device__ __forceinline__ unsigned short f2bf(float f) {
    __hip_bfloat16 h = __float2bfloat16(f);
    return *(unsigned short*)&h;
}

// ---------------- fused preprocessing: zero cnt | cvt W1 | cvt W2 | zero hs ----
// ranges: [0,196) zero cnt, [196,452) cvt1, [452,516) cvt2, [516,644) zero hs
#define PREP_BLOCKS 644

__global__ __launch_bounds__(256) void k_prep(const float* __restrict__ W1,
                                              const float* __restrict__ W2,
                                              unsigned short* __restrict__ wt1,
                                              unsigned short* __restrict__ wt2,
                                              int* __restrict__ cnt,
                                              float* __restrict__ hs) {
    int b = blockIdx.x;
    int t = threadIdx.x;
    if (b < 196) {
        int i = b * 256 + t;
        if (i < N_NODES) cnt[i] = 0;
    } else if (b < 452) {
        int idx = (b - 196) * 256 + t;
        int n = idx & 127, k = idx >> 7;
        wt1[(size_t)n * IN_FEATS + k] = f2bf(W1[(size_t)k * 128 + n]);
    } else if (b < 516) {
        int idx = (b - 452) * 256 + t;
        int n = idx & 127, k = idx >> 7;
        wt2[(size_t)n * HID + k] = f2bf(W2[(size_t)k * 128 + n]);
    } else {
        int idx = (b - 516) * 256 + t;
        hs[idx] = 0.f;
    }
}

// ------- FAT kernel: GEMM1 (wave = 16 rows x 64 cols, LDS-free, barrier-free) + edge count ----
// gemm: Cb[M,128]bf16 = A[M,K]fp32 @ Bt[128][K]bf16^T
// 6250 wave-units: unit = (strip s, col-half ch). Lane l: A row m0+(l&15),
// k-chunk (l>>4)*8 (32B contiguous per lane). B frag direct from global (L1/L2-hot,
// wave pairs in a block share strip/half -> broadcast hits).
// 2-deep register pipeline, enforced with sched_barrier(0) so the scheduler
// cannot sink prefetch loads into the MFMA cluster (round-1 failure: VGPR=48
// proved the pipeline was collapsed). No barriers -> counted vmcnt, loads
// stay in flight across K-steps.

__device__ __forceinline__ short8 cvt8(float4 x, float4 y) {
    short8 r;
    r[0] = (short)f2bf(x.x); r[1] = (short)f2bf(x.y);
    r[2] = (short)f2bf(x.z); r[3] = (short)f2bf(x.w);
    r[4] = (short)f2bf(y.x); r[5] = (short)f2bf(y.y);
    r[6] = (short)f2bf(y.z); r[7] = (short)f2bf(y.w);
    return r;
}

template <int K>
__global__ __launch_bounds__(256, 4) void k_g1c(const float* __restrict__ A,
                                                const unsigned short* __restrict__ Bt,
                                                unsigned short* __restrict__ Cb, int M,
                                                const int* __restrict__ col,
                                                int* __restrict__ cnt, int nblk_gemm) {
    int tid = threadIdx.x;

    if (blockIdx.x >= nblk_gemm) {
        // -------- edge count part --------
        int e4 = ((blockIdx.x - nblk_gemm) * 256 + tid) * 4;
        if (e4 < N_EDGES) {
            int4 c = *(const int4*)(col + e4);
            atomicAdd(&cnt[c.x], 1);
            atomicAdd(&cnt[c.y], 1);
            atomicAdd(&cnt[c.z], 1);
            atomicAdd(&cnt[c.w], 1);
        }
        return;
    }

    // -------- gemm1 part --------
    int wave = tid >> 6;
    int lane = tid & 63;
    int quad = lane >> 4;
    int l15 = lane & 15;
    int unit = blockIdx.x * 4 + wave;
    int nunits = (M >> 4) * 2;              // 6250 (M % 16 == 0)
    if (unit >= nunits) return;
    int s  = unit >> 1;                     // 16-row strip
    int ch = unit & 1;                      // column half
    int m0 = s * 16;

    const float* ap = A + (size_t)(m0 + l15) * K + quad * 8;
    const unsigned short* bp = Bt + (size_t)(ch * 64 + l15) * K + quad * 8;

    f32x4 acc0 = (f32x4){0.f,0.f,0.f,0.f}, acc1 = acc0, acc2 = acc0, acc3 = acc0;

#define LOADA(v0, v1, k)  { v0 = *(const float4*)(ap + (k)); v1 = *(const float4*)(ap + (k) + 4); }
#define LOADB(b0, b1, b2, b3, k) { \
    b0 = *(const short8*)(bp + (size_t)0 * 16 * K + (k)); \
    b1 = *(const short8*)(bp + (size_t)1 * 16 * K + (k)); \
    b2 = *(const short8*)(bp + (size_t)2 * 16 * K + (k)); \
    b3 = *(const short8*)(bp + (size_t)3 * 16 * K + (k)); }
#define MFMA4(af, b0, b1, b2, b3) { \
    acc0 = __builtin_amdgcn_mfma_f32_16x16x32_bf16(af, b0, acc0, 0, 0, 0); \
    acc1 = __builtin_amdgcn_mfma_f32_16x16x32_bf16(af, b1, acc1, 0, 0, 0); \
    acc2 = __builtin_amdgcn_mfma_f32_16x16x32_bf16(af, b2, acc2, 0, 0, 0); \
    acc3 = __builtin_amdgcn_mfma_f32_16x16x32_bf16(af, b3, acc3, 0, 0, 0); }

    float4 aA0, aA1, aB0, aB1;
    short8 bA0, bA1, bA2, bA3, bB0, bB1, bB2, bB3;
    LOADA(aA0, aA1, 0); LOADB(bA0, bA1, bA2, bA3, 0);
    LOADA(aB0, aB1, 32); LOADB(bB0, bB1, bB2, bB3, 32);

#pragma unroll 1
    for (int k0 = 0; k0 < K - 64; k0 += 64) {
        // even half-step: prefetch k0+64, compute k0
        {
            float4 nA0, nA1; short8 nB0, nB1, nB2, nB3;
            LOADA(nA0, nA1, k0 + 64); LOADB(nB0, nB1, nB2, nB3, k0 + 64);
            __builtin_amdgcn_sched_barrier(0);
            short8 af = cvt8(aA0, aA1);
            MFMA4(af, bA0, bA1, bA2, bA3);
            aA0 = nA0; aA1 = nA1;
            bA0 = nB0; bA1 = nB1; bA2 = nB2; bA3 = nB3;
        }
        // odd half-step: prefetch k0+96, compute k0+32
        {
            float4 mA0, mA1; short8 mB0, mB1, mB2, mB3;
            LOADA(mA0, mA1, k0 + 96); LOADB(mB0, mB1, mB2, mB3, k0 + 96);
            __builtin_amdgcn_sched_barrier(0);
            short8 af = cvt8(aB0, aB1);
            MFMA4(af, bB0, bB1, bB2, bB3);
            aB0 = mA0; aB1 = mA1;
            bB0 = mB0; bB1 = mB1; bB2 = mB2; bB3 = mB3;
        }
    }
    {   // tail K-steps: K-64 and K-32
        short8 af = cvt8(aA0, aA1);
        MFMA4(af, bA0, bA1, bA2, bA3);
        af = cvt8(aB0, aB1);
        MFMA4(af, bB0, bB1, bB2, bB3);
    }
#undef LOADA
#undef LOADB
#undef MFMA4

    // store: C row = m0 + quad*4 + r2, col = ch*64 + nt*16 + l15 (M % 16 == 0, no clamp)
    f32x4 accs[4] = {acc0, acc1, acc2, acc3};
#pragma unroll
    for (int nt = 0; nt < 4; ++nt) {
        int colb = ch * 64 + nt * 16 + l15;
#pragma unroll
        for (int r2 = 0; r2 < 4; ++r2) {
            int gm = m0 + quad * 4 + r2;
            Cb[(size_t)gm * 128 + colb] = f2bf(accs[nt][r2]);
        }
    }
}

// ---------------- scan ----------------

__global__ __launch_bounds__(256) void k_scan_a(const int* __restrict__ cnt,
                                                int* __restrict__ offs,
                                                int* __restrict__ bsum) {
    __shared__ int sums[256];
    int t = threadIdx.x;
    int base = blockIdx.x * SCAN_CHUNK + t * 4;
    int c0 = 0, c1 = 0, c2 = 0, c3 = 0;
    if (base + 3 < N_NODES) {
        int4 v = *(const int4*)(cnt + base);
        c0 = v.x; c1 = v.y; c2 = v.z; c3 = v.w;
    } else {
        if (base + 0 < N_NODES) c0 = cnt[base + 0];
        if (base + 1 < N_NODES) c1 = cnt[base + 1];
        if (base + 2 < N_NODES) c2 = cnt[base + 2];
    }
    int ts = c0 + c1 + c2 + c3;
    sums[t] = ts;
    __syncthreads();
#pragma unroll
    for (int off = 1; off < 256; off <<= 1) {
        int add = (t >= off) ? sums[t - off] : 0;
        __syncthreads();
        sums[t] += add;
        __syncthreads();
    }
    int ex = sums[t] - ts;
    if (base + 3 < N_NODES) {
        int4 o;
        o.x = ex; o.y = ex + c0; o.z = ex + c0 + c1; o.w = ex + c0 + c1 + c2;
        *(int4*)(offs + base) = o;
    } else {
        if (base + 0 < N_NODES) offs[base + 0] = ex;
        if (base + 1 < N_NODES) offs[base + 1] = ex + c0;
        if (base + 2 < N_NODES) offs[base + 2] = ex + c0 + c1;
    }
    if (t == 255) bsum[blockIdx.x] = sums[255];
}

__global__ __launch_bounds__(256) void k_scan_c(const int* __restrict__ cnt,
                                                const int* __restrict__ bsum,
                                                int* __restrict__ offs,
                                                int* __restrict__ cursor,
                                                float* __restrict__ dinv) {
    __shared__ int sb[64];
    int t = threadIdx.x;
    int b = blockIdx.x;
    if (t < 64) sb[t] = (t < SCAN_BLOCKS) ? bsum[t] : 0;
    __syncthreads();
#pragma unroll
    for (int off = 1; off < 64; off <<= 1) {
        int add = 0;
        if (t < 64 && t >= off) add = sb[t - off];
        __syncthreads();
        if (t < 64) sb[t] += add;
        __syncthreads();
    }
    int add = (b == 0) ? 0 : sb[b - 1];
    int base = b * SCAN_CHUNK + t * 4;
    if (base + 3 < N_NODES) {
        int4 o = *(const int4*)(offs + base);
        o.x += add; o.y += add; o.z += add; o.w += add;
        *(int4*)(offs + base) = o;
        *(int4*)(cursor + base) = o;
        int4 c = *(const int4*)(cnt + base);
        float4 d;
        d.x = rsqrtf((float)c.x + 1.0f);
        d.y = rsqrtf((float)c.y + 1.0f);
        d.z = rsqrtf((float)c.z + 1.0f);
        d.w = rsqrtf((float)c.w + 1.0f);
        *(float4*)(dinv + base) = d;
    } else {
#pragma unroll
        for (int j = 0; j < 4; ++j) {
            int i = base + j;
            if (i < N_NODES) {
                int o = offs[i] + add;
                offs[i] = o; cursor[i] = o;
                dinv[i] = rsqrtf((float)cnt[i] + 1.0f);
            }
        }
    }
    if (b == 0 && t == 0) offs[N_NODES] = N_EDGES;
}

__global__ void k_fill(const int* __restrict__ row, const int* __restrict__ col,
                       int* __restrict__ cursor, int* __restrict__ srcIdx) {
    int e4 = (blockIdx.x * blockDim.x + threadIdx.x) * 4;
    if (e4 >= N_EDGES) return;
    int4 r = *(const int4*)(row + e4);
    int4 c = *(const int4*)(col + e4);
    srcIdx[atomicAdd(&cursor[c.x], 1)] = r.x;
    srcIdx[atomicAdd(&cursor[c.y], 1)] = r.y;
    srcIdx[atomicAdd(&cursor[c.z], 1)] = r.z;
    srcIdx[atomicAdd(&cursor[c.w], 1)] = r.w;
}

// ---------------- aggregation: one WAVE per node, 2 edges/iter (half-wave parity) ----
// t rows are 64 uints (128 bf16). Lane l=lane&31 covers uints [2l,2l+1] = feats 4l..4l+3;
// half h=lane>>5 takes edge e+h. Predicated 16-edge chunks: invalid slots gather own row
// with weight 0 (cache-hot, exact). Cross-half combine via shfl_xor 32.

template <int RELU>
__global__ __launch_bounds__(256) void k_agg(const unsigned* __restrict__ t,
                                             const int* __restrict__ offs,
                                             const int* __restrict__ srcIdx,
                                             const float* __restrict__ dinv,
                                             const float* __restrict__ bias,
                                             unsigned* __restrict__ out_) {
    int wave = threadIdx.x >> 6;
    int lane = threadIdx.x & 63;
    int h = lane >> 5;
    int l = lane & 31;
    int i = blockIdx.x * 4 + wave;          // N_NODES % 4 == 0
    float di = dinv[i];
    const unsigned* my = t + (size_t)i * 64 + 2 * l;

    float s0 = 0.f, s1 = 0.f, s2 = 0.f, s3 = 0.f;
    {   // self term, half 0 only
        uint2 sv = *(const uint2*)my;
        if (h == 0) {
            s0 = bf2f(sv.x & 0xffffu) * di;
            s1 = bf2f(sv.x >> 16) * di;
            s2 = bf2f(sv.y & 0xffffu) * di;
            s3 = bf2f(sv.y >> 16) * di;
        }
    }
    int lo = offs[i], hi = offs[i + 1];
    for (int e = lo; e < hi; e += 16) {
        int idx[8];
        float d[8];
        uint2 v[8];
#pragma unroll
        for (int j = 0; j < 8; ++j) {
            int ee = e + 2 * j + h;
            idx[j] = (ee < hi) ? srcIdx[ee] : i;     // self row when invalid
        }
#pragma unroll
        for (int j = 0; j < 8; ++j)
            v[j] = *(const uint2*)(t + (size_t)idx[j] * 64 + 2 * l);
#pragma unroll
        for (int j = 0; j < 8; ++j) {
            int ee = e + 2 * j + h;
            d[j] = (ee < hi) ? dinv[idx[j]] : 0.f;   // weight 0 when invalid
        }
#pragma unroll
        for (int j = 0; j < 8; ++j) {
            s0 = fmaf(bf2f(v[j].x & 0xffffu), d[j], s0);
            s1 = fmaf(bf2f(v[j].x >> 16),     d[j], s1);
            s2 = fmaf(bf2f(v[j].y & 0xffffu), d[j], s2);
            s3 = fmaf(bf2f(v[j].y >> 16),     d[j], s3);
        }
    }
    // combine the two halves
    s0 += __shfl_xor(s0, 32);
    s1 += __shfl_xor(s1, 32);
    s2 += __shfl_xor(s2, 32);
    s3 += __shfl_xor(s3, 32);

    float r0 = s0 * di, r1 = s1 * di, r2 = s2 * di, r3 = s3 * di;
    if (bias) {
        float4 bb = *(const float4*)(bias + 4 * l);
        r0 += bb.x; r1 += bb.y; r2 += bb.z; r3 += bb.w;
    }
    if (RELU) {
        r0 = fmaxf(r0, 0.f); r1 = fmaxf(r1, 0.f);
        r2 = fmaxf(r2, 0.f); r3 = fmaxf(r3, 0.f);
    }
    if (h == 0) {
        uint2 o;
        o.x = (unsigned)f2bf(r0) | ((unsigned)f2bf(r1) << 16);
        o.y = (unsigned)f2bf(r2) | ((unsigned)f2bf(r3) << 16);
        *(uint2*)(out_ + (size_t)i * 64 + 2 * l) = o;
    }
}

// ------- GEMM2 + bias + fused pool: out[M,128]f32 = G[M,128]bf16 @ Bt^T + b;
//         hs[batch[m]] += out[m]  (rows batch-sorted -> grouped atomics) -------

__global__ __launch_bounds__(256) void k_gemm2_pool(const unsigned short* __restrict__ G,
                                                    const unsigned short* __restrict__ Bt,
                                                    const float* __restrict__ bias,
                                                    const int* __restrict__ batch,
                                                    float* __restrict__ out,
                                                    float* __restrict__ hs, int M) {
    const int K = HID;
    __shared__ unsigned short As[4][64][8];
    __shared__ unsigned short Bs[4][128][8];
    int tid = threadIdx.x;
    int wave = tid >> 6;
    int lane = tid & 63;
    int quad = lane >> 4;
    int l15 = lane & 15;
    int m0 = blockIdx.x * 64;

    f32x4 acc[8];
#pragma unroll
    for (int nt = 0; nt < 8; ++nt) acc[nt] = (f32x4){0.f, 0.f, 0.f, 0.f};

    int gm_a = m0 + lane; if (gm_a >= M) gm_a = M - 1;
    const unsigned short* ap_base = G + (size_t)gm_a * K + wave * 8;

    for (int k0 = 0; k0 < K; k0 += 32) {
        *(short8*)&As[wave][lane][0] = *(const short8*)(ap_base + k0);
#pragma unroll
        for (int i = 0; i < 2; ++i) {
            int slot = tid + i * 256;
            int bkq = slot >> 7;
            int n = slot & 127;
            *(short8*)&Bs[bkq][n][0] = *(const short8*)(Bt + (size_t)n * K + k0 + bkq * 8);
        }
        __syncthreads();
        short8 a = *(short8*)&As[quad][wave * 16 + l15][0];
#pragma unroll
        for (int nt = 0; nt < 8; ++nt) {
            short8 b = *(short8*)&Bs[quad][nt * 16 + l15][0];
            acc[nt] = __builtin_amdgcn_mfma_f32_16x16x32_bf16(a, b, acc[nt], 0, 0, 0);
        }
        __syncthreads();
    }
    int rb = m0 + wave * 16 + quad * 4;
    int g_[4];
#pragma unroll
    for (int r2 = 0; r2 < 4; ++r2)
        g_[r2] = (rb + r2 < M) ? batch[rb + r2] : -1;
#pragma unroll
    for (int nt = 0; nt < 8; ++nt) {
        int colb = nt * 16 + l15;
        float bcol = bias[colb];
        float v[4];
#pragma unroll
        for (int r2 = 0; r2 < 4; ++r2) {
            v[r2] = acc[nt][r2] + bcol;
            if (rb + r2 < M) out[(size_t)(rb + r2) * 128 + colb] = v[r2];
        }
        float run = v[0];
        int gcur = g_[0];
#pragma unroll
        for (int r2 = 1; r2 < 4; ++r2) {
            if (g_[r2] == gcur) run += v[r2];
            else {
                if (gcur >= 0) atomicAdd(&hs[(size_t)gcur * 128 + colb], run);
                gcur = g_[r2]; run = v[r2];
            }
        }
        if (gcur >= 0) atomicAdd(&hs[(size_t)gcur * 128 + colb], run);
    }
}

// ---------------- launch ----------------

extern "C" void kernel_launch(void* const* d_in, const int* in_sizes, int n_in,
                              void* d_out, int out_size, void* d_ws, size_t ws_size,
                              hipStream_t stream) {
    const float* x  = (const float*)d_in[0];
    const float* W1 = (const float*)d_in[1];
    const float* b1 = (const float*)d_in[2];
    const float* W2 = (const float*)d_in[3];
    const float* b2 = (const float*)d_in[4];
    const int*   ei = (const int*)d_in[5];
    const int*   batch = (const int*)d_in[6];
    const int* row = ei;
    const int* col = ei + N_EDGES;

    float* out_hs = (float*)d_out;
    float* out_h  = (float*)d_out + N_GRAPHS * OUT_FEATS;

    char* ws = (char*)d_ws;
    unsigned short* tb   = (unsigned short*)ws;                  // 12,800,000
    unsigned short* h1b  = (unsigned short*)(ws + 12800000);     // 12,800,000
    unsigned short* gb   = (unsigned short*)(ws + 25600000);     // 12,800,000
    float* dinv = (float*)(ws + 38400000);
    int*   cnt    = (int*)(ws + 38600000);
    int*   offs   = (int*)(ws + 38800000);
    int*   cursor = (int*)(ws + 39000016);
    int*   srcIdx = (int*)(ws + 39200016);
    int*   bsum   = (int*)(ws + 41761056);
    unsigned short* wt1 = (unsigned short*)(ws + 41761472);
    unsigned short* wt2 = (unsigned short*)(ws + 41892544);

    const int TB = 256;
    const int NUNITS = (N_NODES / 16) * 2;               // 6250 wave-units
    const int GB1 = (NUNITS + 3) / 4;                    // 1563 gemm blocks
    const int CB  = (N_EDGES / 4 + TB - 1) / TB;         // 625 count blocks

    k_prep<<<PREP_BLOCKS, 256, 0, stream>>>(W1, W2, wt1, wt2, cnt, out_hs);
    // gemm1 + edge-count fat kernel (independent work, concurrent)
    k_g1c<IN_FEATS><<<GB1 + CB, 256, 0, stream>>>(x, wt1, tb, N_NODES, col, cnt, GB1);
    k_scan_a<<<SCAN_BLOCKS, 256, 0, stream>>>(cnt, offs, bsum);
    k_scan_c<<<SCAN_BLOCKS, 256, 0, stream>>>(cnt, bsum, offs, cursor, dinv);
    k_fill<<<(N_EDGES / 4 + TB - 1) / TB, TB, 0, stream>>>(row, col, cursor, srcIdx);

    // layer 1 agg (+b1, ReLU) -> bf16 h1
    k_agg<1><<<N_NODES / 4, 256, 0, stream>>>((const unsigned*)tb, offs, srcIdx, dinv, b1, (unsigned*)h1b);
    // layer 2 (commuted): agg h1 (no bias) -> g, then GEMM2 (+b2) with fused pool
    k_agg<0><<<N_NODES / 4, 256, 0, stream>>>((const unsigned*)h1b, offs, srcIdx, dinv, nullptr, (unsigned*)gb);
    k_gemm2_pool<<<(N_NODES + 63) / 64, 256, 0, stream>>>(gb, wt2, b2, batch, out_h, out_hs, N_NODES);
}

// Round 3
// 329.784 us; speedup vs baseline: 1.1154x; 1.1154x over previous
//
#include <hip/hip_runtime.h>
#include <hip/hip_bf16.h>

#define N_NODES  50000
#define N_EDGES  640000
#define IN_FEATS 512
#define HID      128
#define OUT_FEATS 128
#define N_GRAPHS 256

#define SCAN_CHUNK 1024
#define SCAN_BLOCKS ((N_NODES + SCAN_CHUNK - 1) / SCAN_CHUNK)   // 49

typedef __attribute__((ext_vector_type(8))) short short8;
typedef __attribute__((ext_vector_type(4))) float f32x4;

__device__ __forceinline__ float bf2f(unsigned u16) {
    return __uint_as_float(u16 << 16);
}
__device__ __forceinline__ unsigned short f2bf(float f) {
    __hip_bfloat16 h = __float2bfloat16(f);
    return *(unsigned short*)&h;
}

__device__ __forceinline__ short8 cvt8(float4 x, float4 y) {
    short8 r;
    r[0] = (short)f2bf(x.x); r[1] = (short)f2bf(x.y);
    r[2] = (short)f2bf(x.z); r[3] = (short)f2bf(x.w);
    r[4] = (short)f2bf(y.x); r[5] = (short)f2bf(y.y);
    r[6] = (short)f2bf(y.z); r[7] = (short)f2bf(y.w);
    return r;
}

// async global->LDS, 16B per lane, dest = uniform base + lane*16
__device__ __forceinline__ void gl_lds16(const void* g, void* l) {
    __builtin_amdgcn_global_load_lds(
        (const __attribute__((address_space(1))) void*)g,
        (__attribute__((address_space(3))) void*)l, 16, 0, 0);
}

// ---------------- fused preprocessing: zero cnt | cvt W1 | cvt W2 | zero hs ----
// ranges: [0,196) zero cnt, [196,452) cvt1, [452,516) cvt2, [516,644) zero hs
#define PREP_BLOCKS 644

__global__ __launch_bounds__(256) void k_prep(const float* __restrict__ W1,
                                              const float* __restrict__ W2,
                                              unsigned short* __restrict__ wt1,
                                              unsigned short* __restrict__ wt2,
                                              int* __restrict__ cnt,
                                              float* __restrict__ hs) {
    int b = blockIdx.x;
    int t = threadIdx.x;
    if (b < 196) {
        int i = b * 256 + t;
        if (i < N_NODES) cnt[i] = 0;
    } else if (b < 452) {
        int idx = (b - 196) * 256 + t;
        int n = idx & 127, k = idx >> 7;
        wt1[(size_t)n * IN_FEATS + k] = f2bf(W1[(size_t)k * 128 + n]);
    } else if (b < 516) {
        int idx = (b - 452) * 256 + t;
        int n = idx & 127, k = idx >> 7;
        wt2[(size_t)n * HID + k] = f2bf(W2[(size_t)k * 128 + n]);
    } else {
        int idx = (b - 516) * 256 + t;
        hs[idx] = 0.f;
    }
}

// ------- FAT kernel: GEMM1 (64x128 tile, dbuf LDS via global_load_lds) + edge count ----
// gemm: Cb[M,128]bf16 = A[M,K]fp32 @ Bt[128][K]bf16^T
// Block = 64 rows x 128 cols, 4 waves as 2x2 (wave quadrant 32x64).
// A staged fp32 as As[buf][h][kq][row][4f]: chunk c = h*256+kq*64+row, lds off = c*16
//   -> fragment ds_read_b128 has 16B row stride = conflict-free. Conversion to bf16
//   happens consumer-side (guide CM#1: no VALU staging).
// B staged as Bs[buf][kq][row][8]bf16: chunk c = kq*128+row.
// Raw s_barrier + counted vmcnt(4): next-tile DMA stays in flight across barriers
// (avoids __syncthreads vmcnt(0) drain). Stage t+2 issued after read-done barrier.

template <int K>
__global__ __launch_bounds__(256, 4) void k_g1c(const float* __restrict__ A,
                                                const unsigned short* __restrict__ Bt,
                                                unsigned short* __restrict__ Cb, int M,
                                                const int* __restrict__ col,
                                                int* __restrict__ cnt, int nblk_gemm) {
    __shared__ float          As[2][2][4][64][4];   // 8 KB / buf
    __shared__ unsigned short Bs[2][4][128][8];     // 8 KB / buf
    int tid = threadIdx.x;

    if (blockIdx.x >= nblk_gemm) {
        // -------- edge count part --------
        int e4 = ((blockIdx.x - nblk_gemm) * 256 + tid) * 4;
        if (e4 < N_EDGES) {
            int4 c = *(const int4*)(col + e4);
            atomicAdd(&cnt[c.x], 1);
            atomicAdd(&cnt[c.y], 1);
            atomicAdd(&cnt[c.z], 1);
            atomicAdd(&cnt[c.w], 1);
        }
        return;
    }

    // -------- gemm1 part --------
    int wave = tid >> 6;
    int lane = tid & 63;
    int quad = lane >> 4;
    int l15 = lane & 15;
    int wm = wave >> 1;          // 0,1 : row half (32 rows)
    int wn = wave & 1;           // 0,1 : col half (64 cols)
    int m0 = blockIdx.x * 64;

    // ---- staging macros: per wave 2 A-issues + 2 B-issues (vmcnt unit = 4/tile) ----
#define STAGE(buf, k0) {                                                        \
    _Pragma("unroll")                                                           \
    for (int is = 0; is < 2; ++is) {                                            \
        int c = (wave * 2 + is) * 64 + lane;                                    \
        int h = c >> 8, kq = (c >> 6) & 3, r = c & 63;                          \
        int gr = m0 + r; if (gr >= M) gr = M - 1;                               \
        const float* g = A + (size_t)gr * K + (k0) + kq * 8 + h * 4;            \
        void* l = (char*)&As[buf][0][0][0][0] + (wave * 2 + is) * 1024;         \
        gl_lds16(g, l);                                                         \
    }                                                                           \
    _Pragma("unroll")                                                           \
    for (int is = 0; is < 2; ++is) {                                            \
        int c = (wave * 2 + is) * 64 + lane;                                    \
        int kq = c >> 7, r = c & 127;                                           \
        const unsigned short* g = Bt + (size_t)r * K + (k0) + kq * 8;           \
        void* l = (char*)&Bs[buf][0][0][0] + (wave * 2 + is) * 1024;            \
        gl_lds16(g, l);                                                         \
    }                                                                           \
}

    f32x4 acc[2][4];
#pragma unroll
    for (int i = 0; i < 2; ++i)
#pragma unroll
        for (int j = 0; j < 4; ++j) acc[i][j] = (f32x4){0.f, 0.f, 0.f, 0.f};

    const int NT = K / 32;       // 16 K-steps
    STAGE(0, 0);
    STAGE(1, 32);

#pragma unroll 1
    for (int t = 0; t < NT; ++t) {
        int buf = t & 1;
        if (t == NT - 1) { asm volatile("s_waitcnt vmcnt(0)" ::: "memory"); }
        else             { asm volatile("s_waitcnt vmcnt(4)" ::: "memory"); }
        __builtin_amdgcn_s_barrier();           // tile t fully in LDS

        // fragment reads (all 16B-stride -> conflict-free) + consumer-side cvt
        float4 lo0 = *(const float4*)&As[buf][0][quad][wm * 32 + l15][0];
        float4 hi0 = *(const float4*)&As[buf][1][quad][wm * 32 + l15][0];
        float4 lo1 = *(const float4*)&As[buf][0][quad][wm * 32 + 16 + l15][0];
        float4 hi1 = *(const float4*)&As[buf][1][quad][wm * 32 + 16 + l15][0];
        short8 bfr[4];
#pragma unroll
        for (int j = 0; j < 4; ++j)
            bfr[j] = *(const short8*)&Bs[buf][quad][wn * 64 + j * 16 + l15][0];

        asm volatile("s_waitcnt lgkmcnt(0)" ::: "memory");
        __builtin_amdgcn_sched_barrier(0);
        __builtin_amdgcn_s_barrier();           // all waves done reading buf

        if (t < NT - 2) STAGE(buf, (t + 2) * 32);
        __builtin_amdgcn_sched_barrier(0);      // keep DMA issue above MFMAs

        short8 a0 = cvt8(lo0, hi0);
        short8 a1 = cvt8(lo1, hi1);
#pragma unroll
        for (int j = 0; j < 4; ++j) {
            acc[0][j] = __builtin_amdgcn_mfma_f32_16x16x32_bf16(a0, bfr[j], acc[0][j], 0, 0, 0);
            acc[1][j] = __builtin_amdgcn_mfma_f32_16x16x32_bf16(a1, bfr[j], acc[1][j], 0, 0, 0);
        }
    }
#undef STAGE

    // store: row = m0 + wm*32 + i*16 + quad*4 + r2, col = wn*64 + j*16 + l15
#pragma unroll
    for (int i = 0; i < 2; ++i) {
        int rb = m0 + wm * 32 + i * 16 + quad * 4;
#pragma unroll
        for (int j = 0; j < 4; ++j) {
            int colb = wn * 64 + j * 16 + l15;
#pragma unroll
            for (int r2 = 0; r2 < 4; ++r2) {
                int gm = rb + r2;
                if (gm < M) Cb[(size_t)gm * 128 + colb] = f2bf(acc[i][j][r2]);
            }
        }
    }
}

// ---------------- scan ----------------

__global__ __launch_bounds__(256) void k_scan_a(const int* __restrict__ cnt,
                                                int* __restrict__ offs,
                                                int* __restrict__ bsum) {
    __shared__ int sums[256];
    int t = threadIdx.x;
    int base = blockIdx.x * SCAN_CHUNK + t * 4;
    int c0 = 0, c1 = 0, c2 = 0, c3 = 0;
    if (base + 3 < N_NODES) {
        int4 v = *(const int4*)(cnt + base);
        c0 = v.x; c1 = v.y; c2 = v.z; c3 = v.w;
    } else {
        if (base + 0 < N_NODES) c0 = cnt[base + 0];
        if (base + 1 < N_NODES) c1 = cnt[base + 1];
        if (base + 2 < N_NODES) c2 = cnt[base + 2];
    }
    int ts = c0 + c1 + c2 + c3;
    sums[t] = ts;
    __syncthreads();
#pragma unroll
    for (int off = 1; off < 256; off <<= 1) {
        int add = (t >= off) ? sums[t - off] : 0;
        __syncthreads();
        sums[t] += add;
        __syncthreads();
    }
    int ex = sums[t] - ts;
    if (base + 3 < N_NODES) {
        int4 o;
        o.x = ex; o.y = ex + c0; o.z = ex + c0 + c1; o.w = ex + c0 + c1 + c2;
        *(int4*)(offs + base) = o;
    } else {
        if (base + 0 < N_NODES) offs[base + 0] = ex;
        if (base + 1 < N_NODES) offs[base + 1] = ex + c0;
        if (base + 2 < N_NODES) offs[base + 2] = ex + c0 + c1;
    }
    if (t == 255) bsum[blockIdx.x] = sums[255];
}

__global__ __launch_bounds__(256) void k_scan_c(const int* __restrict__ cnt,
                                                const int* __restrict__ bsum,
                                                int* __restrict__ offs,
                                                int* __restrict__ cursor,
                                                float* __restrict__ dinv) {
    __shared__ int sb[64];
    int t = threadIdx.x;
    int b = blockIdx.x;
    if (t < 64) sb[t] = (t < SCAN_BLOCKS) ? bsum[t] : 0;
    __syncthreads();
#pragma unroll
    for (int off = 1; off < 64; off <<= 1) {
        int add = 0;
        if (t < 64 && t >= off) add = sb[t - off];
        __syncthreads();
        if (t < 64) sb[t] += add;
        __syncthreads();
    }
    int add = (b == 0) ? 0 : sb[b - 1];
    int base = b * SCAN_CHUNK + t * 4;
    if (base + 3 < N_NODES) {
        int4 o = *(const int4*)(offs + base);
        o.x += add; o.y += add; o.z += add; o.w += add;
        *(int4*)(offs + base) = o;
        *(int4*)(cursor + base) = o;
        int4 c = *(const int4*)(cnt + base);
        float4 d;
        d.x = rsqrtf((float)c.x + 1.0f);
        d.y = rsqrtf((float)c.y + 1.0f);
        d.z = rsqrtf((float)c.z + 1.0f);
        d.w = rsqrtf((float)c.w + 1.0f);
        *(float4*)(dinv + base) = d;
    } else {
#pragma unroll
        for (int j = 0; j < 4; ++j) {
            int i = base + j;
            if (i < N_NODES) {
                int o = offs[i] + add;
                offs[i] = o; cursor[i] = o;
                dinv[i] = rsqrtf((float)cnt[i] + 1.0f);
            }
        }
    }
    if (b == 0 && t == 0) offs[N_NODES] = N_EDGES;
}

__global__ void k_fill(const int* __restrict__ row, const int* __restrict__ col,
                       int* __restrict__ cursor, int* __restrict__ srcIdx) {
    int e4 = (blockIdx.x * blockDim.x + threadIdx.x) * 4;
    if (e4 >= N_EDGES) return;
    int4 r = *(const int4*)(row + e4);
    int4 c = *(const int4*)(col + e4);
    srcIdx[atomicAdd(&cursor[c.x], 1)] = r.x;
    srcIdx[atomicAdd(&cursor[c.y], 1)] = r.y;
    srcIdx[atomicAdd(&cursor[c.z], 1)] = r.z;
    srcIdx[atomicAdd(&cursor[c.w], 1)] = r.w;
}

// ---------------- aggregation: one WAVE per node, 2 edges/iter (half-wave parity) ----
// t rows are 64 uints (128 bf16). Lane l=lane&31 covers uints [2l,2l+1] = feats 4l..4l+3;
// half h=lane>>5 takes edge e+h. Predicated 16-edge chunks: invalid slots gather own row
// with weight 0 (cache-hot, exact). Cross-half combine via shfl_xor 32.

template <int RELU>
__global__ __launch_bounds__(256) void k_agg(const unsigned* __restrict__ t,
                                             const int* __restrict__ offs,
                                             const int* __restrict__ srcIdx,
                                             const float* __restrict__ dinv,
                                             const float* __restrict__ bias,
                                             unsigned* __restrict__ out_) {
    int wave = threadIdx.x >> 6;
    int lane = threadIdx.x & 63;
    int h = lane >> 5;
    int l = lane & 31;
    int i = blockIdx.x * 4 + wave;          // N_NODES % 4 == 0
    float di = dinv[i];
    const unsigned* my = t + (size_t)i * 64 + 2 * l;

    float s0 = 0.f, s1 = 0.f, s2 = 0.f, s3 = 0.f;
    {   // self term, half 0 only
        uint2 sv = *(const uint2*)my;
        if (h == 0) {
            s0 = bf2f(sv.x & 0xffffu) * di;
            s1 = bf2f(sv.x >> 16) * di;
            s2 = bf2f(sv.y & 0xffffu) * di;
            s3 = bf2f(sv.y >> 16) * di;
        }
    }
    int lo = offs[i], hi = offs[i + 1];
    for (int e = lo; e < hi; e += 16) {
        int idx[8];
        float d[8];
        uint2 v[8];
#pragma unroll
        for (int j = 0; j < 8; ++j) {
            int ee = e + 2 * j + h;
            idx[j] = (ee < hi) ? srcIdx[ee] : i;     // self row when invalid
        }
#pragma unroll
        for (int j = 0; j < 8; ++j)
            v[j] = *(const uint2*)(t + (size_t)idx[j] * 64 + 2 * l);
#pragma unroll
        for (int j = 0; j < 8; ++j) {
            int ee = e + 2 * j + h;
            d[j] = (ee < hi) ? dinv[idx[j]] : 0.f;   // weight 0 when invalid
        }
#pragma unroll
        for (int j = 0; j < 8; ++j) {
            s0 = fmaf(bf2f(v[j].x & 0xffffu), d[j], s0);
            s1 = fmaf(bf2f(v[j].x >> 16),     d[j], s1);
            s2 = fmaf(bf2f(v[j].y & 0xffffu), d[j], s2);
            s3 = fmaf(bf2f(v[j].y >> 16),     d[j], s3);
        }
    }
    // combine the two halves
    s0 += __shfl_xor(s0, 32);
    s1 += __shfl_xor(s1, 32);
    s2 += __shfl_xor(s2, 32);
    s3 += __shfl_xor(s3, 32);

    float r0 = s0 * di, r1 = s1 * di, r2 = s2 * di, r3 = s3 * di;
    if (bias) {
        float4 bb = *(const float4*)(bias + 4 * l);
        r0 += bb.x; r1 += bb.y; r2 += bb.z; r3 += bb.w;
    }
    if (RELU) {
        r0 = fmaxf(r0, 0.f); r1 = fmaxf(r1, 0.f);
        r2 = fmaxf(r2, 0.f); r3 = fmaxf(r3, 0.f);
    }
    if (h == 0) {
        uint2 o;
        o.x = (unsigned)f2bf(r0) | ((unsigned)f2bf(r1) << 16);
        o.y = (unsigned)f2bf(r2) | ((unsigned)f2bf(r3) << 16);
        *(uint2*)(out_ + (size_t)i * 64 + 2 * l) = o;
    }
}

// ------- GEMM2 + bias + fused pool: out[M,128]f32 = G[M,128]bf16 @ Bt^T + b;
//         hs[batch[m]] += out[m]  (rows batch-sorted -> grouped atomics) -------

__global__ __launch_bounds__(256) void k_gemm2_pool(const unsigned short* __restrict__ G,
                                                    const unsigned short* __restrict__ Bt,
                                                    const float* __restrict__ bias,
                                                    const int* __restrict__ batch,
                                                    float* __restrict__ out,
                                                    float* __restrict__ hs, int M) {
    const int K = HID;
    __shared__ unsigned short As[4][64][8];
    __shared__ unsigned short Bs[4][128][8];
    int tid = threadIdx.x;
    int wave = tid >> 6;
    int lane = tid & 63;
    int quad = lane >> 4;
    int l15 = lane & 15;
    int m0 = blockIdx.x * 64;

    f32x4 acc[8];
#pragma unroll
    for (int nt = 0; nt < 8; ++nt) acc[nt] = (f32x4){0.f, 0.f, 0.f, 0.f};

    int gm_a = m0 + lane; if (gm_a >= M) gm_a = M - 1;
    const unsigned short* ap_base = G + (size_t)gm_a * K + wave * 8;

    for (int k0 = 0; k0 < K; k0 += 32) {
        *(short8*)&As[wave][lane][0] = *(const short8*)(ap_base + k0);
#pragma unroll
        for (int i = 0; i < 2; ++i) {
            int slot = tid + i * 256;
            int bkq = slot >> 7;
            int n = slot & 127;
            *(short8*)&Bs[bkq][n][0] = *(const short8*)(Bt + (size_t)n * K + k0 + bkq * 8);
        }
        __syncthreads();
        short8 a = *(short8*)&As[quad][wave * 16 + l15][0];
#pragma unroll
        for (int nt = 0; nt < 8; ++nt) {
            short8 b = *(short8*)&Bs[quad][nt * 16 + l15][0];
            acc[nt] = __builtin_amdgcn_mfma_f32_16x16x32_bf16(a, b, acc[nt], 0, 0, 0);
        }
        __syncthreads();
    }
    int rb = m0 + wave * 16 + quad * 4;
    int g_[4];
#pragma unroll
    for (int r2 = 0; r2 < 4; ++r2)
        g_[r2] = (rb + r2 < M) ? batch[rb + r2] : -1;
#pragma unroll
    for (int nt = 0; nt < 8; ++nt) {
        int colb = nt * 16 + l15;
        float bcol = bias[colb];
        float v[4];
#pragma unroll
        for (int r2 = 0; r2 < 4; ++r2) {
            v[r2] = acc[nt][r2] + bcol;
            if (rb + r2 < M) out[(size_t)(rb + r2) * 128 + colb] = v[r2];
        }
        float run = v[0];
        int gcur = g_[0];
#pragma unroll
        for (int r2 = 1; r2 < 4; ++r2) {
            if (g_[r2] == gcur) run += v[r2];
            else {
                if (gcur >= 0) atomicAdd(&hs[(size_t)gcur * 128 + colb], run);
                gcur = g_[r2]; run = v[r2];
            }
        }
        if (gcur >= 0) atomicAdd(&hs[(size_t)gcur * 128 + colb], run);
    }
}

// ---------------- launch ----------------

extern "C" void kernel_launch(void* const* d_in, const int* in_sizes, int n_in,
                              void* d_out, int out_size, void* d_ws, size_t ws_size,
                              hipStream_t stream) {
    const float* x  = (const float*)d_in[0];
    const float* W1 = (const float*)d_in[1];
    const float* b1 = (const float*)d_in[2];
    const float* W2 = (const float*)d_in[3];
    const float* b2 = (const float*)d_in[4];
    const int*   ei = (const int*)d_in[5];
    const int*   batch = (const int*)d_in[6];
    const int* row = ei;
    const int* col = ei + N_EDGES;

    float* out_hs = (float*)d_out;
    float* out_h  = (float*)d_out + N_GRAPHS * OUT_FEATS;

    char* ws = (char*)d_ws;
    unsigned short* tb   = (unsigned short*)ws;                  // 12,800,000
    unsigned short* h1b  = (unsigned short*)(ws + 12800000);     // 12,800,000
    unsigned short* gb   = (unsigned short*)(ws + 25600000);     // 12,800,000
    float* dinv = (float*)(ws + 38400000);
    int*   cnt    = (int*)(ws + 38600000);
    int*   offs   = (int*)(ws + 38800000);
    int*   cursor = (int*)(ws + 39000016);
    int*   srcIdx = (int*)(ws + 39200016);
    int*   bsum   = (int*)(ws + 41761056);
    unsigned short* wt1 = (unsigned short*)(ws + 41761472);
    unsigned short* wt2 = (unsigned short*)(ws + 41892544);

    const int TB = 256;
    const int GB1 = (N_NODES + 63) / 64;                 // 782 gemm blocks (64x128 tile)
    const int CB  = (N_EDGES / 4 + TB - 1) / TB;         // 625 count blocks

    k_prep<<<PREP_BLOCKS, 256, 0, stream>>>(W1, W2, wt1, wt2, cnt, out_hs);
    // gemm1 + edge-count fat kernel (independent work, concurrent)
    k_g1c<IN_FEATS><<<GB1 + CB, 256, 0, stream>>>(x, wt1, tb, N_NODES, col, cnt, GB1);
    k_scan_a<<<SCAN_BLOCKS, 256, 0, stream>>>(cnt, offs, bsum);
    k_scan_c<<<SCAN_BLOCKS, 256, 0, stream>>>(cnt, bsum, offs, cursor, dinv);
    k_fill<<<(N_EDGES / 4 + TB - 1) / TB, TB, 0, stream>>>(row, col, cursor, srcIdx);

    // layer 1 agg (+b1, ReLU) -> bf16 h1
    k_agg<1><<<N_NODES / 4, 256, 0, stream>>>((const unsigned*)tb, offs, srcIdx, dinv, b1, (unsigned*)h1b);
    // layer 2 (commuted): agg h1 (no bias) -> g, then GEMM2 (+b2) with fused pool
    k_agg<0><<<N_NODES / 4, 256, 0, stream>>>((const unsigned*)h1b, offs, srcIdx, dinv, nullptr, (unsigned*)gb);
    k_gemm2_pool<<<(N_NODES + 63) / 64, 256, 0, stream>>>(gb, wt2, b2, batch, out_h, out_hs, N_NODES);
}

// Round 4
// 321.289 us; speedup vs baseline: 1.1449x; 1.0264x over previous
//
#include <hip/hip_runtime.h>
#include <hip/hip_bf16.h>

#define N_NODES  50000
#define N_EDGES  640000
#define IN_FEATS 512
#define HID      128
#define OUT_FEATS 128
#define N_GRAPHS 256

#define SCAN_CHUNK 1024
#define SCAN_BLOCKS ((N_NODES + SCAN_CHUNK - 1) / SCAN_CHUNK)   // 49

typedef __attribute__((ext_vector_type(8))) short short8;
typedef __attribute__((ext_vector_type(4))) float f32x4;

__device__ __forceinline__ float bf2f(unsigned u16) {
    return __uint_as_float(u16 << 16);
}
__device__ __forceinline__ unsigned short f2bf(float f) {
    __hip_bfloat16 h = __float2bfloat16(f);
    return *(unsigned short*)&h;
}

__device__ __forceinline__ short8 cvt8(float4 x, float4 y) {
    short8 r;
    r[0] = (short)f2bf(x.x); r[1] = (short)f2bf(x.y);
    r[2] = (short)f2bf(x.z); r[3] = (short)f2bf(x.w);
    r[4] = (short)f2bf(y.x); r[5] = (short)f2bf(y.y);
    r[6] = (short)f2bf(y.z); r[7] = (short)f2bf(y.w);
    return r;
}

// async global->LDS, 16B per lane, dest = wave-uniform base + lane*16
__device__ __forceinline__ void gl_lds16(const void* g, void* l) {
    __builtin_amdgcn_global_load_lds(
        (const __attribute__((address_space(1))) void*)g,
        (__attribute__((address_space(3))) void*)l, 16, 0, 0);
}

// ---------------- fused preprocessing: zero cnt | cvt W1 | cvt W2 | zero hs ----
// ranges: [0,196) zero cnt, [196,452) cvt1, [452,516) cvt2, [516,644) zero hs
#define PREP_BLOCKS 644

__global__ __launch_bounds__(256) void k_prep(const float* __restrict__ W1,
                                              const float* __restrict__ W2,
                                              unsigned short* __restrict__ wt1,
                                              unsigned short* __restrict__ wt2,
                                              int* __restrict__ cnt,
                                              float* __restrict__ hs) {
    int b = blockIdx.x;
    int t = threadIdx.x;
    if (b < 196) {
        int i = b * 256 + t;
        if (i < N_NODES) cnt[i] = 0;
    } else if (b < 452) {
        int idx = (b - 196) * 256 + t;
        int n = idx & 127, k = idx >> 7;
        wt1[(size_t)n * IN_FEATS + k] = f2bf(W1[(size_t)k * 128 + n]);
    } else if (b < 516) {
        int idx = (b - 452) * 256 + t;
        int n = idx & 127, k = idx >> 7;
        wt2[(size_t)n * HID + k] = f2bf(W2[(size_t)k * 128 + n]);
    } else {
        int idx = (b - 516) * 256 + t;
        hs[idx] = 0.f;
    }
}

// ------- FAT kernel: GEMM1 (64x128 tile, BK=64, coalesced DMA staging) + edge count ----
// gemm: Cb[M,128]bf16 = A[M,K]fp32 @ Bt[128][K]bf16^T
// Block = 64 rows x 128 cols, 4 waves as 2x2 (wave quadrant 32x64). BK=64, NT=8.
//
// Staging is COALESCED: each global_load_lds covers contiguous 1KB of A/B
// (A: 4 rows x 256B = 8 cache lines/instr; B: 8 rows x 128B = 8 lines/instr)
// vs the old 64-lines/instr row-scatter (the round-3 bottleneck: address-pipe
// serialization at ~1 line/cy made k_g1c request-rate bound at 72us).
// LDS is written linearly -> natural row-major tile; bank conflicts on the
// fragment ds_read_b128 are avoided by XOR-swizzling the CONTENT: physical
// 16B-chunk p of row r holds logical chunk p ^ (r&7) (pre-swizzled global
// source, guide m173 pattern). Reads use the same XOR -> 2-way max = free.
// Raw s_barrier + counted vmcnt(8): next-tile DMA stays in flight across
// barriers. Stage t+2 issued after the read-done barrier.

template <int K>
__global__ __launch_bounds__(256, 2) void k_g1c(const float* __restrict__ A,
                                                const unsigned short* __restrict__ Bt,
                                                unsigned short* __restrict__ Cb, int M,
                                                const int* __restrict__ col,
                                                int* __restrict__ cnt, int nblk_gemm) {
    __shared__ float          As[2][64][64];    // 16 KB / buf  (row = 256B = 16 chunks)
    __shared__ unsigned short Bs[2][128][64];   // 16 KB / buf  (row = 128B = 8 chunks)
    int tid = threadIdx.x;

    if (blockIdx.x >= nblk_gemm) {
        // -------- edge count part --------
        int e4 = ((blockIdx.x - nblk_gemm) * 256 + tid) * 4;
        if (e4 < N_EDGES) {
            int4 c = *(const int4*)(col + e4);
            atomicAdd(&cnt[c.x], 1);
            atomicAdd(&cnt[c.y], 1);
            atomicAdd(&cnt[c.z], 1);
            atomicAdd(&cnt[c.w], 1);
        }
        return;
    }

    // -------- gemm1 part --------
    int wave = tid >> 6;
    int lane = tid & 63;
    int quad = lane >> 4;
    int l15 = lane & 15;
    int wm = wave >> 1;          // 0,1 : row half (32 rows)
    int wn = wave & 1;           // 0,1 : col half (64 cols)
    int m0 = blockIdx.x * 64;

    // per tile, per wave: 4 A-issues + 4 B-issues -> vmcnt unit = 8/tile
#define STAGE(buf, k0) {                                                        \
    _Pragma("unroll")                                                           \
    for (int is = 0; is < 4; ++is) {                                            \
        int a_ = wave * 4 + is;                    /* instr id 0..15 */         \
        int c = a_ * 64 + lane;                    /* chunk 0..1023 */          \
        int r = c >> 4, pcol = c & 15;                                          \
        int lcol = pcol ^ (r & 7);                                              \
        int gr = m0 + r; if (gr >= M) gr = M - 1;                               \
        const float* g = A + (size_t)gr * K + (k0) + lcol * 4;                  \
        void* l = (char*)&As[buf][0][0] + a_ * 1024;                            \
        gl_lds16(g, l);                                                         \
    }                                                                           \
    _Pragma("unroll")                                                           \
    for (int is = 0; is < 4; ++is) {                                            \
        int a_ = wave * 4 + is;                                                 \
        int c = a_ * 64 + lane;                                                 \
        int r = c >> 3, pcol = c & 7;                                           \
        int lcol = pcol ^ (r & 7);                                              \
        const unsigned short* g = Bt + (size_t)r * K + (k0) + lcol * 8;         \
        void* l = (char*)&Bs[buf][0][0] + a_ * 1024;                            \
        gl_lds16(g, l);                                                         \
    }                                                                           \
}

    f32x4 acc[2][4];
#pragma unroll
    for (int i = 0; i < 2; ++i)
#pragma unroll
        for (int j = 0; j < 4; ++j) acc[i][j] = (f32x4){0.f, 0.f, 0.f, 0.f};

    const int NT = K / 64;       // 8 tiles
    STAGE(0, 0);
    STAGE(1, 64);

#pragma unroll 1
    for (int t = 0; t < NT; ++t) {
        int buf = t & 1;
        if (t == NT - 1) { asm volatile("s_waitcnt vmcnt(0)" ::: "memory"); }
        else             { asm volatile("s_waitcnt vmcnt(8)" ::: "memory"); }
        __builtin_amdgcn_s_barrier();           // tile t fully in LDS

        // ---- fragment reads (XOR-swizzled, 2-way max bank alias = free) ----
        const char* abase = (const char*)&As[buf][0][0];
        const char* bbase = (const char*)&Bs[buf][0][0];
        float4 ax[2][2], ay[2][2];              // [kh][i]
#pragma unroll
        for (int kh = 0; kh < 2; ++kh)
#pragma unroll
            for (int i = 0; i < 2; ++i) {
                int r = wm * 32 + i * 16 + l15;
                int lc = kh * 8 + quad * 2;
                int p0 = lc ^ (r & 7);          // lc even -> p1 = p0 ^ 1
                ax[kh][i] = *(const float4*)(abase + r * 256 + p0 * 16);
                ay[kh][i] = *(const float4*)(abase + r * 256 + (p0 ^ 1) * 16);
            }
        short8 bfr[2][4];                       // [kh][j]
#pragma unroll
        for (int kh = 0; kh < 2; ++kh)
#pragma unroll
            for (int j = 0; j < 4; ++j) {
                int r = wn * 64 + j * 16 + l15;
                int lc = kh * 4 + quad;
                int p = lc ^ (r & 7);
                bfr[kh][j] = *(const short8*)(bbase + r * 128 + p * 16);
            }

        asm volatile("s_waitcnt lgkmcnt(0)" ::: "memory");
        __builtin_amdgcn_sched_barrier(0);
        __builtin_amdgcn_s_barrier();           // all waves done reading buf

        if (t < NT - 2) STAGE(buf, (t + 2) * 64);
        __builtin_amdgcn_sched_barrier(0);      // keep DMA issue above MFMAs

#pragma unroll
        for (int kh = 0; kh < 2; ++kh) {
            short8 a0 = cvt8(ax[kh][0], ay[kh][0]);
            short8 a1 = cvt8(ax[kh][1], ay[kh][1]);
#pragma unroll
            for (int j = 0; j < 4; ++j) {
                acc[0][j] = __builtin_amdgcn_mfma_f32_16x16x32_bf16(a0, bfr[kh][j], acc[0][j], 0, 0, 0);
                acc[1][j] = __builtin_amdgcn_mfma_f32_16x16x32_bf16(a1, bfr[kh][j], acc[1][j], 0, 0, 0);
            }
        }
    }
#undef STAGE

    // store: row = m0 + wm*32 + i*16 + quad*4 + r2, col = wn*64 + j*16 + l15
#pragma unroll
    for (int i = 0; i < 2; ++i) {
        int rb = m0 + wm * 32 + i * 16 + quad * 4;
#pragma unroll
        for (int j = 0; j < 4; ++j) {
            int colb = wn * 64 + j * 16 + l15;
#pragma unroll
            for (int r2 = 0; r2 < 4; ++r2) {
                int gm = rb + r2;
                if (gm < M) Cb[(size_t)gm * 128 + colb] = f2bf(acc[i][j][r2]);
            }
        }
    }
}

// ---------------- scan ----------------

__global__ __launch_bounds__(256) void k_scan_a(const int* __restrict__ cnt,
                                                int* __restrict__ offs,
                                                int* __restrict__ bsum) {
    __shared__ int sums[256];
    int t = threadIdx.x;
    int base = blockIdx.x * SCAN_CHUNK + t * 4;
    int c0 = 0, c1 = 0, c2 = 0, c3 = 0;
    if (base + 3 < N_NODES) {
        int4 v = *(const int4*)(cnt + base);
        c0 = v.x; c1 = v.y; c2 = v.z; c3 = v.w;
    } else {
        if (base + 0 < N_NODES) c0 = cnt[base + 0];
        if (base + 1 < N_NODES) c1 = cnt[base + 1];
        if (base + 2 < N_NODES) c2 = cnt[base + 2];
    }
    int ts = c0 + c1 + c2 + c3;
    sums[t] = ts;
    __syncthreads();
#pragma unroll
    for (int off = 1; off < 256; off <<= 1) {
        int add = (t >= off) ? sums[t - off] : 0;
        __syncthreads();
        sums[t] += add;
        __syncthreads();
    }
    int ex = sums[t] - ts;
    if (base + 3 < N_NODES) {
        int4 o;
        o.x = ex; o.y = ex + c0; o.z = ex + c0 + c1; o.w = ex + c0 + c1 + c2;
        *(int4*)(offs + base) = o;
    } else {
        if (base + 0 < N_NODES) offs[base + 0] = ex;
        if (base + 1 < N_NODES) offs[base + 1] = ex + c0;
        if (base + 2 < N_NODES) offs[base + 2] = ex + c0 + c1;
    }
    if (t == 255) bsum[blockIdx.x] = sums[255];
}

__global__ __launch_bounds__(256) void k_scan_c(const int* __restrict__ cnt,
                                                const int* __restrict__ bsum,
                                                int* __restrict__ offs,
                                                int* __restrict__ cursor,
                                                float* __restrict__ dinv) {
    __shared__ int sb[64];
    int t = threadIdx.x;
    int b = blockIdx.x;
    if (t < 64) sb[t] = (t < SCAN_BLOCKS) ? bsum[t] : 0;
    __syncthreads();
#pragma unroll
    for (int off = 1; off < 64; off <<= 1) {
        int add = 0;
        if (t < 64 && t >= off) add = sb[t - off];
        __syncthreads();
        if (t < 64) sb[t] += add;
        __syncthreads();
    }
    int add = (b == 0) ? 0 : sb[b - 1];
    int base = b * SCAN_CHUNK + t * 4;
    if (base + 3 < N_NODES) {
        int4 o = *(const int4*)(offs + base);
        o.x += add; o.y += add; o.z += add; o.w += add;
        *(int4*)(offs + base) = o;
        *(int4*)(cursor + base) = o;
        int4 c = *(const int4*)(cnt + base);
        float4 d;
        d.x = rsqrtf((float)c.x + 1.0f);
        d.y = rsqrtf((float)c.y + 1.0f);
        d.z = rsqrtf((float)c.z + 1.0f);
        d.w = rsqrtf((float)c.w + 1.0f);
        *(float4*)(dinv + base) = d;
    } else {
#pragma unroll
        for (int j = 0; j < 4; ++j) {
            int i = base + j;
            if (i < N_NODES) {
                int o = offs[i] + add;
                offs[i] = o; cursor[i] = o;
                dinv[i] = rsqrtf((float)cnt[i] + 1.0f);
            }
        }
    }
    if (b == 0 && t == 0) offs[N_NODES] = N_EDGES;
}

__global__ void k_fill(const int* __restrict__ row, const int* __restrict__ col,
                       int* __restrict__ cursor, int* __restrict__ srcIdx) {
    int e4 = (blockIdx.x * blockDim.x + threadIdx.x) * 4;
    if (e4 >= N_EDGES) return;
    int4 r = *(const int4*)(row + e4);
    int4 c = *(const int4*)(col + e4);
    srcIdx[atomicAdd(&cursor[c.x], 1)] = r.x;
    srcIdx[atomicAdd(&cursor[c.y], 1)] = r.y;
    srcIdx[atomicAdd(&cursor[c.z], 1)] = r.z;
    srcIdx[atomicAdd(&cursor[c.w], 1)] = r.w;
}

// ---------------- aggregation: one WAVE per node, 2 edges/iter (half-wave parity) ----
// t rows are 64 uints (128 bf16). Lane l=lane&31 covers uints [2l,2l+1] = feats 4l..4l+3;
// half h=lane>>5 takes edge e+h. Predicated 16-edge chunks: invalid slots gather own row
// with weight 0 (cache-hot, exact). Cross-half combine via shfl_xor 32.

template <int RELU>
__global__ __launch_bounds__(256) void k_agg(const unsigned* __restrict__ t,
                                             const int* __restrict__ offs,
                                             const int* __restrict__ srcIdx,
                                             const float* __restrict__ dinv,
                                             const float* __restrict__ bias,
                                             unsigned* __restrict__ out_) {
    int wave = threadIdx.x >> 6;
    int lane = threadIdx.x & 63;
    int h = lane >> 5;
    int l = lane & 31;
    int i = blockIdx.x * 4 + wave;          // N_NODES % 4 == 0
    float di = dinv[i];
    const unsigned* my = t + (size_t)i * 64 + 2 * l;

    float s0 = 0.f, s1 = 0.f, s2 = 0.f, s3 = 0.f;
    {   // self term, half 0 only
        uint2 sv = *(const uint2*)my;
        if (h == 0) {
            s0 = bf2f(sv.x & 0xffffu) * di;
            s1 = bf2f(sv.x >> 16) * di;
            s2 = bf2f(sv.y & 0xffffu) * di;
            s3 = bf2f(sv.y >> 16) * di;
        }
    }
    int lo = offs[i], hi = offs[i + 1];
    for (int e = lo; e < hi; e += 16) {
        int idx[8];
        float d[8];
        uint2 v[8];
#pragma unroll
        for (int j = 0; j < 8; ++j) {
            int ee = e + 2 * j + h;
            idx[j] = (ee < hi) ? srcIdx[ee] : i;     // self row when invalid
        }
#pragma unroll
        for (int j = 0; j < 8; ++j)
            v[j] = *(const uint2*)(t + (size_t)idx[j] * 64 + 2 * l);
#pragma unroll
        for (int j = 0; j < 8; ++j) {
            int ee = e + 2 * j + h;
            d[j] = (ee < hi) ? dinv[idx[j]] : 0.f;   // weight 0 when invalid
        }
#pragma unroll
        for (int j = 0; j < 8; ++j) {
            s0 = fmaf(bf2f(v[j].x & 0xffffu), d[j], s0);
            s1 = fmaf(bf2f(v[j].x >> 16),     d[j], s1);
            s2 = fmaf(bf2f(v[j].y & 0xffffu), d[j], s2);
            s3 = fmaf(bf2f(v[j].y >> 16),     d[j], s3);
        }
    }
    // combine the two halves
    s0 += __shfl_xor(s0, 32);
    s1 += __shfl_xor(s1, 32);
    s2 += __shfl_xor(s2, 32);
    s3 += __shfl_xor(s3, 32);

    float r0 = s0 * di, r1 = s1 * di, r2 = s2 * di, r3 = s3 * di;
    if (bias) {
        float4 bb = *(const float4*)(bias + 4 * l);
        r0 += bb.x; r1 += bb.y; r2 += bb.z; r3 += bb.w;
    }
    if (RELU) {
        r0 = fmaxf(r0, 0.f); r1 = fmaxf(r1, 0.f);
        r2 = fmaxf(r2, 0.f); r3 = fmaxf(r3, 0.f);
    }
    if (h == 0) {
        uint2 o;
        o.x = (unsigned)f2bf(r0) | ((unsigned)f2bf(r1) << 16);
        o.y = (unsigned)f2bf(r2) | ((unsigned)f2bf(r3) << 16);
        *(uint2*)(out_ + (size_t)i * 64 + 2 * l) = o;
    }
}

// ------- GEMM2 + bias + fused pool: out[M,128]f32 = G[M,128]bf16 @ Bt^T + b;
//         hs[batch[m]] += out[m]  (rows batch-sorted -> grouped atomics) -------

__global__ __launch_bounds__(256) void k_gemm2_pool(const unsigned short* __restrict__ G,
                                                    const unsigned short* __restrict__ Bt,
                                                    const float* __restrict__ bias,
                                                    const int* __restrict__ batch,
                                                    float* __restrict__ out,
                                                    float* __restrict__ hs, int M) {
    const int K = HID;
    __shared__ unsigned short As[4][64][8];
    __shared__ unsigned short Bs[4][128][8];
    int tid = threadIdx.x;
    int wave = tid >> 6;
    int lane = tid & 63;
    int quad = lane >> 4;
    int l15 = lane & 15;
    int m0 = blockIdx.x * 64;

    f32x4 acc[8];
#pragma unroll
    for (int nt = 0; nt < 8; ++nt) acc[nt] = (f32x4){0.f, 0.f, 0.f, 0.f};

    int gm_a = m0 + lane; if (gm_a >= M) gm_a = M - 1;
    const unsigned short* ap_base = G + (size_t)gm_a * K + wave * 8;

    for (int k0 = 0; k0 < K; k0 += 32) {
        *(short8*)&As[wave][lane][0] = *(const short8*)(ap_base + k0);
#pragma unroll
        for (int i = 0; i < 2; ++i) {
            int slot = tid + i * 256;
            int bkq = slot >> 7;
            int n = slot & 127;
            *(short8*)&Bs[bkq][n][0] = *(const short8*)(Bt + (size_t)n * K + k0 + bkq * 8);
        }
        __syncthreads();
        short8 a = *(short8*)&As[quad][wave * 16 + l15][0];
#pragma unroll
        for (int nt = 0; nt < 8; ++nt) {
            short8 b = *(short8*)&Bs[quad][nt * 16 + l15][0];
            acc[nt] = __builtin_amdgcn_mfma_f32_16x16x32_bf16(a, b, acc[nt], 0, 0, 0);
        }
        __syncthreads();
    }
    int rb = m0 + wave * 16 + quad * 4;
    int g_[4];
#pragma unroll
    for (int r2 = 0; r2 < 4; ++r2)
        g_[r2] = (rb + r2 < M) ? batch[rb + r2] : -1;
#pragma unroll
    for (int nt = 0; nt < 8; ++nt) {
        int colb = nt * 16 + l15;
        float bcol = bias[colb];
        float v[4];
#pragma unroll
        for (int r2 = 0; r2 < 4; ++r2) {
            v[r2] = acc[nt][r2] + bcol;
            if (rb + r2 < M) out[(size_t)(rb + r2) * 128 + colb] = v[r2];
        }
        float run = v[0];
        int gcur = g_[0];
#pragma unroll
        for (int r2 = 1; r2 < 4; ++r2) {
            if (g_[r2] == gcur) run += v[r2];
            else {
                if (gcur >= 0) atomicAdd(&hs[(size_t)gcur * 128 + colb], run);
                gcur = g_[r2]; run = v[r2];
            }
        }
        if (gcur >= 0) atomicAdd(&hs[(size_t)gcur * 128 + colb], run);
    }
}

// ---------------- launch ----------------

extern "C" void kernel_launch(void* const* d_in, const int* in_sizes, int n_in,
                              void* d_out, int out_size, void* d_ws, size_t ws_size,
                              hipStream_t stream) {
    const float* x  = (const float*)d_in[0];
    const float* W1 = (const float*)d_in[1];
    const float* b1 = (const float*)d_in[2];
    const float* W2 = (const float*)d_in[3];
    const float* b2 = (const float*)d_in[4];
    const int*   ei = (const int*)d_in[5];
    const int*   batch = (const int*)d_in[6];
    const int* row = ei;
    const int* col = ei + N_EDGES;

    float* out_hs = (float*)d_out;
    float* out_h  = (float*)d_out + N_GRAPHS * OUT_FEATS;

    char* ws = (char*)d_ws;
    unsigned short* tb   = (unsigned short*)ws;                  // 12,800,000
    unsigned short* h1b  = (unsigned short*)(ws + 12800000);     // 12,800,000
    unsigned short* gb   = (unsigned short*)(ws + 25600000);     // 12,800,000
    float* dinv = (float*)(ws + 38400000);
    int*   cnt    = (int*)(ws + 38600000);
    int*   offs   = (int*)(ws + 38800000);
    int*   cursor = (int*)(ws + 39000016);
    int*   srcIdx = (int*)(ws + 39200016);
    int*   bsum   = (int*)(ws + 41761056);
    unsigned short* wt1 = (unsigned short*)(ws + 41761472);
    unsigned short* wt2 = (unsigned short*)(ws + 41892544);

    const int TB = 256;
    const int GB1 = (N_NODES + 63) / 64;                 // 782 gemm blocks (64x128 tile)
    const int CB  = (N_EDGES / 4 + TB - 1) / TB;         // 625 count blocks

    k_prep<<<PREP_BLOCKS, 256, 0, stream>>>(W1, W2, wt1, wt2, cnt, out_hs);
    // gemm1 + edge-count fat kernel (independent work, concurrent)
    k_g1c<IN_FEATS><<<GB1 + CB, 256, 0, stream>>>(x, wt1, tb, N_NODES, col, cnt, GB1);
    k_scan_a<<<SCAN_BLOCKS, 256, 0, stream>>>(cnt, offs, bsum);
    k_scan_c<<<SCAN_BLOCKS, 256, 0, stream>>>(cnt, bsum, offs, cursor, dinv);
    k_fill<<<(N_EDGES / 4 + TB - 1) / TB, TB, 0, stream>>>(row, col, cursor, srcIdx);

    // layer 1 agg (+b1, ReLU) -> bf16 h1
    k_agg<1><<<N_NODES / 4, 256, 0, stream>>>((const unsigned*)tb, offs, srcIdx, dinv, b1, (unsigned*)h1b);
    // layer 2 (commuted): agg h1 (no bias) -> g, then GEMM2 (+b2) with fused pool
    k_agg<0><<<N_NODES / 4, 256, 0, stream>>>((const unsigned*)h1b, offs, srcIdx, dinv, nullptr, (unsigned*)gb);
    k_gemm2_pool<<<(N_NODES + 63) / 64, 256, 0, stream>>>(gb, wt2, b2, batch, out_h, out_hs, N_NODES);
}

// Round 5
// 309.233 us; speedup vs baseline: 1.1895x; 1.0390x over previous
//
#include <hip/hip_runtime.h>
#include <hip/hip_bf16.h>

#define N_NODES  50000
#define N_EDGES  640000
#define IN_FEATS 512
#define HID      128
#define OUT_FEATS 128
#define N_GRAPHS 256

#define SCAN_CHUNK 1024
#define SCAN_BLOCKS ((N_NODES + SCAN_CHUNK - 1) / SCAN_CHUNK)   // 49

typedef __attribute__((ext_vector_type(8))) short short8;
typedef __attribute__((ext_vector_type(4))) float f32x4;

__device__ __forceinline__ float bf2f(unsigned u16) {
    return __uint_as_float(u16 << 16);
}
__device__ __forceinline__ unsigned short f2bf(float f) {
    __hip_bfloat16 h = __float2bfloat16(f);
    return *(unsigned short*)&h;
}

__device__ __forceinline__ short8 cvt8(float4 x, float4 y) {
    short8 r;
    r[0] = (short)f2bf(x.x); r[1] = (short)f2bf(x.y);
    r[2] = (short)f2bf(x.z); r[3] = (short)f2bf(x.w);
    r[4] = (short)f2bf(y.x); r[5] = (short)f2bf(y.y);
    r[6] = (short)f2bf(y.z); r[7] = (short)f2bf(y.w);
    return r;
}

// async global->LDS, 16B per lane, dest = wave-uniform base + lane*16
__device__ __forceinline__ void gl_lds16(const void* g, void* l) {
    __builtin_amdgcn_global_load_lds(
        (const __attribute__((address_space(1))) void*)g,
        (__attribute__((address_space(3))) void*)l, 16, 0, 0);
}

// ---------------- fused preprocessing: zero cnt | cvt W1 | cvt W2 | zero hs ----
// ranges: [0,196) zero cnt, [196,452) cvt1, [452,516) cvt2, [516,644) zero hs
#define PREP_BLOCKS 644

__global__ __launch_bounds__(256) void k_prep(const float* __restrict__ W1,
                                              const float* __restrict__ W2,
                                              unsigned short* __restrict__ wt1,
                                              unsigned short* __restrict__ wt2,
                                              int* __restrict__ cnt,
                                              float* __restrict__ hs) {
    int b = blockIdx.x;
    int t = threadIdx.x;
    if (b < 196) {
        int i = b * 256 + t;
        if (i < N_NODES) cnt[i] = 0;
    } else if (b < 452) {
        int idx = (b - 196) * 256 + t;
        int n = idx & 127, k = idx >> 7;
        wt1[(size_t)n * IN_FEATS + k] = f2bf(W1[(size_t)k * 128 + n]);
    } else if (b < 516) {
        int idx = (b - 452) * 256 + t;
        int n = idx & 127, k = idx >> 7;
        wt2[(size_t)n * HID + k] = f2bf(W2[(size_t)k * 128 + n]);
    } else {
        int idx = (b - 516) * 256 + t;
        hs[idx] = 0.f;
    }
}

// ------- FAT kernel: GEMM1 (64x128 tile, BK=64, coalesced DMA staging) + edge count ----
// (unchanged from round 4 — 62us, best measured; this round targets the other kernels)

template <int K>
__global__ __launch_bounds__(256, 2) void k_g1c(const float* __restrict__ A,
                                                const unsigned short* __restrict__ Bt,
                                                unsigned short* __restrict__ Cb, int M,
                                                const int* __restrict__ col,
                                                int* __restrict__ cnt, int nblk_gemm) {
    __shared__ float          As[2][64][64];    // 16 KB / buf  (row = 256B = 16 chunks)
    __shared__ unsigned short Bs[2][128][64];   // 16 KB / buf  (row = 128B = 8 chunks)
    int tid = threadIdx.x;

    if (blockIdx.x >= nblk_gemm) {
        // -------- edge count part --------
        int e4 = ((blockIdx.x - nblk_gemm) * 256 + tid) * 4;
        if (e4 < N_EDGES) {
            int4 c = *(const int4*)(col + e4);
            atomicAdd(&cnt[c.x], 1);
            atomicAdd(&cnt[c.y], 1);
            atomicAdd(&cnt[c.z], 1);
            atomicAdd(&cnt[c.w], 1);
        }
        return;
    }

    // -------- gemm1 part --------
    int wave = tid >> 6;
    int lane = tid & 63;
    int quad = lane >> 4;
    int l15 = lane & 15;
    int wm = wave >> 1;          // 0,1 : row half (32 rows)
    int wn = wave & 1;           // 0,1 : col half (64 cols)
    int m0 = blockIdx.x * 64;

    // per tile, per wave: 4 A-issues + 4 B-issues -> vmcnt unit = 8/tile
#define STAGE(buf, k0) {                                                        \
    _Pragma("unroll")                                                           \
    for (int is = 0; is < 4; ++is) {                                            \
        int a_ = wave * 4 + is;                    /* instr id 0..15 */         \
        int c = a_ * 64 + lane;                    /* chunk 0..1023 */          \
        int r = c >> 4, pcol = c & 15;                                          \
        int lcol = pcol ^ (r & 7);                                              \
        int gr = m0 + r; if (gr >= M) gr = M - 1;                               \
        const float* g = A + (size_t)gr * K + (k0) + lcol * 4;                  \
        void* l = (char*)&As[buf][0][0] + a_ * 1024;                            \
        gl_lds16(g, l);                                                         \
    }                                                                           \
    _Pragma("unroll")                                                           \
    for (int is = 0; is < 4; ++is) {                                            \
        int a_ = wave * 4 + is;                                                 \
        int c = a_ * 64 + lane;                                                 \
        int r = c >> 3, pcol = c & 7;                                           \
        int lcol = pcol ^ (r & 7);                                              \
        const unsigned short* g = Bt + (size_t)r * K + (k0) + lcol * 8;         \
        void* l = (char*)&Bs[buf][0][0] + a_ * 1024;                            \
        gl_lds16(g, l);                                                         \
    }                                                                           \
}

    f32x4 acc[2][4];
#pragma unroll
    for (int i = 0; i < 2; ++i)
#pragma unroll
        for (int j = 0; j < 4; ++j) acc[i][j] = (f32x4){0.f, 0.f, 0.f, 0.f};

    const int NT = K / 64;       // 8 tiles
    STAGE(0, 0);
    STAGE(1, 64);

#pragma unroll 1
    for (int t = 0; t < NT; ++t) {
        int buf = t & 1;
        if (t == NT - 1) { asm volatile("s_waitcnt vmcnt(0)" ::: "memory"); }
        else             { asm volatile("s_waitcnt vmcnt(8)" ::: "memory"); }
        __builtin_amdgcn_s_barrier();           // tile t fully in LDS

        // ---- fragment reads (XOR-swizzled, 2-way max bank alias = free) ----
        const char* abase = (const char*)&As[buf][0][0];
        const char* bbase = (const char*)&Bs[buf][0][0];
        float4 ax[2][2], ay[2][2];              // [kh][i]
#pragma unroll
        for (int kh = 0; kh < 2; ++kh)
#pragma unroll
            for (int i = 0; i < 2; ++i) {
                int r = wm * 32 + i * 16 + l15;
                int lc = kh * 8 + quad * 2;
                int p0 = lc ^ (r & 7);          // lc even -> p1 = p0 ^ 1
                ax[kh][i] = *(const float4*)(abase + r * 256 + p0 * 16);
                ay[kh][i] = *(const float4*)(abase + r * 256 + (p0 ^ 1) * 16);
            }
        short8 bfr[2][4];                       // [kh][j]
#pragma unroll
        for (int kh = 0; kh < 2; ++kh)
#pragma unroll
            for (int j = 0; j < 4; ++j) {
                int r = wn * 64 + j * 16 + l15;
                int lc = kh * 4 + quad;
                int p = lc ^ (r & 7);
                bfr[kh][j] = *(const short8*)(bbase + r * 128 + p * 16);
            }

        asm volatile("s_waitcnt lgkmcnt(0)" ::: "memory");
        __builtin_amdgcn_sched_barrier(0);
        __builtin_amdgcn_s_barrier();           // all waves done reading buf

        if (t < NT - 2) STAGE(buf, (t + 2) * 64);
        __builtin_amdgcn_sched_barrier(0);      // keep DMA issue above MFMAs

#pragma unroll
        for (int kh = 0; kh < 2; ++kh) {
            short8 a0 = cvt8(ax[kh][0], ay[kh][0]);
            short8 a1 = cvt8(ax[kh][1], ay[kh][1]);
#pragma unroll
            for (int j = 0; j < 4; ++j) {
                acc[0][j] = __builtin_amdgcn_mfma_f32_16x16x32_bf16(a0, bfr[kh][j], acc[0][j], 0, 0, 0);
                acc[1][j] = __builtin_amdgcn_mfma_f32_16x16x32_bf16(a1, bfr[kh][j], acc[1][j], 0, 0, 0);
            }
        }
    }
#undef STAGE

    // store: row = m0 + wm*32 + i*16 + quad*4 + r2, col = wn*64 + j*16 + l15
#pragma unroll
    for (int i = 0; i < 2; ++i) {
        int rb = m0 + wm * 32 + i * 16 + quad * 4;
#pragma unroll
        for (int j = 0; j < 4; ++j) {
            int colb = wn * 64 + j * 16 + l15;
#pragma unroll
            for (int r2 = 0; r2 < 4; ++r2) {
                int gm = rb + r2;
                if (gm < M) Cb[(size_t)gm * 128 + colb] = f2bf(acc[i][j][r2]);
            }
        }
    }
}

// ---------------- scan ----------------

__global__ __launch_bounds__(256) void k_scan_a(const int* __restrict__ cnt,
                                                int* __restrict__ offs,
                                                int* __restrict__ bsum) {
    __shared__ int sums[256];
    int t = threadIdx.x;
    int base = blockIdx.x * SCAN_CHUNK + t * 4;
    int c0 = 0, c1 = 0, c2 = 0, c3 = 0;
    if (base + 3 < N_NODES) {
        int4 v = *(const int4*)(cnt + base);
        c0 = v.x; c1 = v.y; c2 = v.z; c3 = v.w;
    } else {
        if (base + 0 < N_NODES) c0 = cnt[base + 0];
        if (base + 1 < N_NODES) c1 = cnt[base + 1];
        if (base + 2 < N_NODES) c2 = cnt[base + 2];
    }
    int ts = c0 + c1 + c2 + c3;
    sums[t] = ts;
    __syncthreads();
#pragma unroll
    for (int off = 1; off < 256; off <<= 1) {
        int add = (t >= off) ? sums[t - off] : 0;
        __syncthreads();
        sums[t] += add;
        __syncthreads();
    }
    int ex = sums[t] - ts;
    if (base + 3 < N_NODES) {
        int4 o;
        o.x = ex; o.y = ex + c0; o.z = ex + c0 + c1; o.w = ex + c0 + c1 + c2;
        *(int4*)(offs + base) = o;
    } else {
        if (base + 0 < N_NODES) offs[base + 0] = ex;
        if (base + 1 < N_NODES) offs[base + 1] = ex + c0;
        if (base + 2 < N_NODES) offs[base + 2] = ex + c0 + c1;
    }
    if (t == 255) bsum[blockIdx.x] = sums[255];
}

__global__ __launch_bounds__(256) void k_scan_c(const int* __restrict__ cnt,
                                                const int* __restrict__ bsum,
                                                int* __restrict__ offs,
                                                int* __restrict__ cursor,
                                                float* __restrict__ dinv) {
    __shared__ int sb[64];
    int t = threadIdx.x;
    int b = blockIdx.x;
    if (t < 64) sb[t] = (t < SCAN_BLOCKS) ? bsum[t] : 0;
    __syncthreads();
#pragma unroll
    for (int off = 1; off < 64; off <<= 1) {
        int add = 0;
        if (t < 64 && t >= off) add = sb[t - off];
        __syncthreads();
        if (t < 64) sb[t] += add;
        __syncthreads();
    }
    int add = (b == 0) ? 0 : sb[b - 1];
    int base = b * SCAN_CHUNK + t * 4;
    if (base + 3 < N_NODES) {
        int4 o = *(const int4*)(offs + base);
        o.x += add; o.y += add; o.z += add; o.w += add;
        *(int4*)(offs + base) = o;
        *(int4*)(cursor + base) = o;
        int4 c = *(const int4*)(cnt + base);
        float4 d;
        d.x = rsqrtf((float)c.x + 1.0f);
        d.y = rsqrtf((float)c.y + 1.0f);
        d.z = rsqrtf((float)c.z + 1.0f);
        d.w = rsqrtf((float)c.w + 1.0f);
        *(float4*)(dinv + base) = d;
    } else {
#pragma unroll
        for (int j = 0; j < 4; ++j) {
            int i = base + j;
            if (i < N_NODES) {
                int o = offs[i] + add;
                offs[i] = o; cursor[i] = o;
                dinv[i] = rsqrtf((float)cnt[i] + 1.0f);
            }
        }
    }
    if (b == 0 && t == 0) offs[N_NODES] = N_EDGES;
}

__global__ void k_fill(const int* __restrict__ row, const int* __restrict__ col,
                       int* __restrict__ cursor, int* __restrict__ srcIdx) {
    int e4 = (blockIdx.x * blockDim.x + threadIdx.x) * 4;
    if (e4 >= N_EDGES) return;
    int4 r = *(const int4*)(row + e4);
    int4 c = *(const int4*)(col + e4);
    srcIdx[atomicAdd(&cursor[c.x], 1)] = r.x;
    srcIdx[atomicAdd(&cursor[c.y], 1)] = r.y;
    srcIdx[atomicAdd(&cursor[c.z], 1)] = r.z;
    srcIdx[atomicAdd(&cursor[c.w], 1)] = r.w;
}

// ---------------- aggregation: one WAVE per node, 4 edges per gather-instr ----
// t rows are 256B (128 bf16 = 16 uint4 chunks). Lane group g=lane>>4 takes edge
// slot e+4j+g; lane l16=lane&15 covers chunk l16 = feats [8*l16, 8*l16+8).
// One uint4 gather instruction covers FOUR source rows (4 groups x 256B) vs the
// old uint2 scheme's two -> half the VMEM instructions in a latency-bound kernel.
// Predicated 16-slot chunks: invalid slots gather own row with weight 0.
// Cross-group combine via shfl_xor 16 then 32.

template <int RELU>
__global__ __launch_bounds__(256) void k_agg(const unsigned* __restrict__ t,
                                             const int* __restrict__ offs,
                                             const int* __restrict__ srcIdx,
                                             const float* __restrict__ dinv,
                                             const float* __restrict__ bias,
                                             unsigned* __restrict__ out_) {
    int wave = threadIdx.x >> 6;
    int lane = threadIdx.x & 63;
    int g = lane >> 4;
    int l16 = lane & 15;
    int i = blockIdx.x * 4 + wave;          // N_NODES % 4 == 0
    float di = dinv[i];

    float s[8];
    {   // self term, group 0 only
        uint4 sv = *((const uint4*)(t + (size_t)i * 64) + l16);
        float w = (g == 0) ? di : 0.f;
        s[0] = bf2f(sv.x & 0xffffu) * w; s[1] = bf2f(sv.x >> 16) * w;
        s[2] = bf2f(sv.y & 0xffffu) * w; s[3] = bf2f(sv.y >> 16) * w;
        s[4] = bf2f(sv.z & 0xffffu) * w; s[5] = bf2f(sv.z >> 16) * w;
        s[6] = bf2f(sv.w & 0xffffu) * w; s[7] = bf2f(sv.w >> 16) * w;
    }
    int lo = offs[i], hi = offs[i + 1];
    for (int e = lo; e < hi; e += 16) {
        int idx[4];
        float d[4];
        uint4 v[4];
#pragma unroll
        for (int j = 0; j < 4; ++j) {
            int ee = e + 4 * j + g;
            idx[j] = (ee < hi) ? srcIdx[ee] : i;     // self row when invalid
        }
#pragma unroll
        for (int j = 0; j < 4; ++j)
            v[j] = *((const uint4*)(t + (size_t)idx[j] * 64) + l16);
#pragma unroll
        for (int j = 0; j < 4; ++j) {
            int ee = e + 4 * j + g;
            d[j] = (ee < hi) ? dinv[idx[j]] : 0.f;   // weight 0 when invalid
        }
#pragma unroll
        for (int j = 0; j < 4; ++j) {
            s[0] = fmaf(bf2f(v[j].x & 0xffffu), d[j], s[0]);
            s[1] = fmaf(bf2f(v[j].x >> 16),     d[j], s[1]);
            s[2] = fmaf(bf2f(v[j].y & 0xffffu), d[j], s[2]);
            s[3] = fmaf(bf2f(v[j].y >> 16),     d[j], s[3]);
            s[4] = fmaf(bf2f(v[j].z & 0xffffu), d[j], s[4]);
            s[5] = fmaf(bf2f(v[j].z >> 16),     d[j], s[5]);
            s[6] = fmaf(bf2f(v[j].w & 0xffffu), d[j], s[6]);
            s[7] = fmaf(bf2f(v[j].w >> 16),     d[j], s[7]);
        }
    }
    // combine the four groups
#pragma unroll
    for (int k = 0; k < 8; ++k) {
        s[k] += __shfl_xor(s[k], 16);
        s[k] += __shfl_xor(s[k], 32);
    }

    float r[8];
#pragma unroll
    for (int k = 0; k < 8; ++k) r[k] = s[k] * di;
    if (bias) {
        float4 b0 = *(const float4*)(bias + 8 * l16);
        float4 b1 = *(const float4*)(bias + 8 * l16 + 4);
        r[0] += b0.x; r[1] += b0.y; r[2] += b0.z; r[3] += b0.w;
        r[4] += b1.x; r[5] += b1.y; r[6] += b1.z; r[7] += b1.w;
    }
    if (RELU) {
#pragma unroll
        for (int k = 0; k < 8; ++k) r[k] = fmaxf(r[k], 0.f);
    }
    if (lane < 16) {
        uint4 o;
        o.x = (unsigned)f2bf(r[0]) | ((unsigned)f2bf(r[1]) << 16);
        o.y = (unsigned)f2bf(r[2]) | ((unsigned)f2bf(r[3]) << 16);
        o.z = (unsigned)f2bf(r[4]) | ((unsigned)f2bf(r[5]) << 16);
        o.w = (unsigned)f2bf(r[6]) | ((unsigned)f2bf(r[7]) << 16);
        *((uint4*)(out_ + (size_t)i * 64) + l16) = o;
    }
}

// ------- GEMM2 + bias + fused pool: out[M,128]f32 = G[M,128]bf16 @ Bt^T + b;
//         hs[batch[m]] += out[m]  (rows batch-sorted -> grouped atomics)
// K=128 is small: stage ALL of W2^T (32 KB) + the 64-row A tile (16 KB, one-shot
// coalesced DMA, content-XOR-swizzled source) -> ONE barrier, then 4 pure-LDS
// MFMA K-steps. Replaces the old 4x(stage+2 syncthreads) loop. 48 KB -> 3 blk/CU.

__global__ __launch_bounds__(256, 3) void k_gemm2_pool(const unsigned short* __restrict__ G,
                                                       const unsigned short* __restrict__ Bt,
                                                       const float* __restrict__ bias,
                                                       const int* __restrict__ batch,
                                                       float* __restrict__ out,
                                                       float* __restrict__ hs, int M) {
    __shared__ unsigned short As[64][128];    // 16 KB, content-swizzled chunks
    __shared__ unsigned short Bs[128][128];   // 32 KB, content-swizzled chunks
    int tid = threadIdx.x;
    int wave = tid >> 6;
    int lane = tid & 63;
    int quad = lane >> 4;
    int l15 = lane & 15;
    int m0 = blockIdx.x * 64;

    // ---- stage A tile via coalesced DMA (16 instrs, 4/wave) ----
#pragma unroll
    for (int is = 0; is < 4; ++is) {
        int a_ = wave * 4 + is;               // instr 0..15
        int c = a_ * 64 + lane;               // chunk 0..1023 (row=16 chunks)
        int r = c >> 4, pcol = c & 15;
        int lcol = pcol ^ (r & 7);
        int gr = m0 + r; if (gr >= M) gr = M - 1;
        const unsigned short* gp = G + (size_t)gr * 128 + lcol * 8;
        void* l = (char*)&As[0][0] + a_ * 1024;
        gl_lds16(gp, l);
    }
    // ---- stage whole B (wt2) via vector stores, content-swizzled ----
#pragma unroll
    for (int it = 0; it < 8; ++it) {
        int idx = it * 256 + tid;             // chunk 0..2047
        int n = idx >> 4, lc = idx & 15;
        int p = lc ^ (n & 7);
        *(uint4*)((char*)&Bs[0][0] + n * 256 + p * 16) =
            *(const uint4*)(Bt + (size_t)n * 128 + lc * 8);
    }
    asm volatile("s_waitcnt vmcnt(0)" ::: "memory");
    __syncthreads();

    f32x4 acc[8];
#pragma unroll
    for (int nt = 0; nt < 8; ++nt) acc[nt] = (f32x4){0.f, 0.f, 0.f, 0.f};

    int ra = wave * 16 + l15;
#pragma unroll
    for (int s = 0; s < 4; ++s) {
        int kc = s * 4 + quad;
        short8 a = *(const short8*)((char*)&As[0][0] + ra * 256 + (kc ^ (ra & 7)) * 16);
#pragma unroll
        for (int nt = 0; nt < 8; ++nt) {
            int rn = nt * 16 + l15;
            short8 b = *(const short8*)((char*)&Bs[0][0] + rn * 256 + (kc ^ (rn & 7)) * 16);
            acc[nt] = __builtin_amdgcn_mfma_f32_16x16x32_bf16(a, b, acc[nt], 0, 0, 0);
        }
    }

    int rb = m0 + wave * 16 + quad * 4;
    int g_[4];
#pragma unroll
    for (int r2 = 0; r2 < 4; ++r2)
        g_[r2] = (rb + r2 < M) ? batch[rb + r2] : -1;
#pragma unroll
    for (int nt = 0; nt < 8; ++nt) {
        int colb = nt * 16 + l15;
        float bcol = bias[colb];
        float v[4];
#pragma unroll
        for (int r2 = 0; r2 < 4; ++r2) {
            v[r2] = acc[nt][r2] + bcol;
            if (rb + r2 < M) out[(size_t)(rb + r2) * 128 + colb] = v[r2];
        }
        float run = v[0];
        int gcur = g_[0];
#pragma unroll
        for (int r2 = 1; r2 < 4; ++r2) {
            if (g_[r2] == gcur) run += v[r2];
            else {
                if (gcur >= 0) atomicAdd(&hs[(size_t)gcur * 128 + colb], run);
                gcur = g_[r2]; run = v[r2];
            }
        }
        if (gcur >= 0) atomicAdd(&hs[(size_t)gcur * 128 + colb], run);
    }
}

// ---------------- launch ----------------

extern "C" void kernel_launch(void* const* d_in, const int* in_sizes, int n_in,
                              void* d_out, int out_size, void* d_ws, size_t ws_size,
                              hipStream_t stream) {
    const float* x  = (const float*)d_in[0];
    const float* W1 = (const float*)d_in[1];
    const float* b1 = (const float*)d_in[2];
    const float* W2 = (const float*)d_in[3];
    const float* b2 = (const float*)d_in[4];
    const int*   ei = (const int*)d_in[5];
    const int*   batch = (const int*)d_in[6];
    const int* row = ei;
    const int* col = ei + N_EDGES;

    float* out_hs = (float*)d_out;
    float* out_h  = (float*)d_out + N_GRAPHS * OUT_FEATS;

    char* ws = (char*)d_ws;
    unsigned short* tb   = (unsigned short*)ws;                  // 12,800,000
    unsigned short* h1b  = (unsigned short*)(ws + 12800000);     // 12,800,000
    unsigned short* gb   = (unsigned short*)(ws + 25600000);     // 12,800,000
    float* dinv = (float*)(ws + 38400000);
    int*   cnt    = (int*)(ws + 38600000);
    int*   offs   = (int*)(ws + 38800000);
    int*   cursor = (int*)(ws + 39000016);
    int*   srcIdx = (int*)(ws + 39200016);
    int*   bsum   = (int*)(ws + 41761056);
    unsigned short* wt1 = (unsigned short*)(ws + 41761472);
    unsigned short* wt2 = (unsigned short*)(ws + 41892544);

    const int TB = 256;
    const int GB1 = (N_NODES + 63) / 64;                 // 782 gemm blocks (64x128 tile)
    const int CB  = (N_EDGES / 4 + TB - 1) / TB;         // 625 count blocks

    k_prep<<<PREP_BLOCKS, 256, 0, stream>>>(W1, W2, wt1, wt2, cnt, out_hs);
    // gemm1 + edge-count fat kernel (independent work, concurrent)
    k_g1c<IN_FEATS><<<GB1 + CB, 256, 0, stream>>>(x, wt1, tb, N_NODES, col, cnt, GB1);
    k_scan_a<<<SCAN_BLOCKS, 256, 0, stream>>>(cnt, offs, bsum);
    k_scan_c<<<SCAN_BLOCKS, 256, 0, stream>>>(cnt, bsum, offs, cursor, dinv);
    k_fill<<<(N_EDGES / 4 + TB - 1) / TB, TB, 0, stream>>>(row, col, cursor, srcIdx);

    // layer 1 agg (+b1, ReLU) -> bf16 h1
    k_agg<1><<<N_NODES / 4, 256, 0, stream>>>((const unsigned*)tb, offs, srcIdx, dinv, b1, (unsigned*)h1b);
    // layer 2 (commuted): agg h1 (no bias) -> g, then GEMM2 (+b2) with fused pool
    k_agg<0><<<N_NODES / 4, 256, 0, stream>>>((const unsigned*)h1b, offs, srcIdx, dinv, nullptr, (unsigned*)gb);
    k_gemm2_pool<<<(N_NODES + 63) / 64, 256, 0, stream>>>(gb, wt2, b2, batch, out_h, out_hs, N_NODES);
}